// Round 6
// baseline (1435.314 us; speedup 1.0000x reference)
//
#include <hip/hip_runtime.h>
#include <hip/hip_cooperative_groups.h>

namespace cg = cooperative_groups;

#define D 2048
#define M 512
#define STEPS 8
#define NBLK 512   // 2 blocks/CU guaranteed co-resident at launch_bounds(256,2)

typedef __attribute__((ext_vector_type(8))) short bf16x8;
typedef __attribute__((ext_vector_type(4))) float f32x4;

__device__ inline unsigned short f2bf(float f) {
    union { float f; unsigned u; } v; v.f = f;
    unsigned r = v.u + 0x7fffu + ((v.u >> 16) & 1u);  // RNE
    return (unsigned short)(r >> 16);
}
__device__ inline float bf2f(unsigned short h) {
    union { float f; unsigned u; } v; v.u = ((unsigned)h) << 16;
    return v.f;
}
__device__ inline uint2 pack4(const unsigned short* h) {
    uint2 u;
    u.x = h[0] | ((unsigned)h[1] << 16);
    u.y = h[2] | ((unsigned)h[3] << 16);
    return u;
}
__device__ inline uint4 pack8(const unsigned short* h) {
    uint4 u;
    u.x = h[0] | ((unsigned)h[1] << 16);
    u.y = h[2] | ((unsigned)h[3] << 16);
    u.z = h[4] | ((unsigned)h[5] << 16);
    u.w = h[6] | ((unsigned)h[7] << 16);
    return u;
}

// 16x16 tile of U·V in split-bf16. aHi/aLo: U rows (pre-offset to row block).
// bHi/bLo: V columns as rows (V^T row-major; for symmetric V, V row-major).
__device__ inline f32x4 mm_tile(const unsigned short* __restrict__ aHi,
                                const unsigned short* __restrict__ aLo, int lda,
                                const unsigned short* __restrict__ bHi,
                                const unsigned short* __restrict__ bLo, int ldb,
                                int K, int lm, int lq) {
    f32x4 a1 = {0.f, 0.f, 0.f, 0.f}, a2 = {0.f, 0.f, 0.f, 0.f};
    const unsigned short* ah = aHi + (size_t)lm * lda + lq * 8;
    const unsigned short* al = aLo + (size_t)lm * lda + lq * 8;
    const unsigned short* bh = bHi + (size_t)lm * ldb + lq * 8;
    const unsigned short* bl = bLo + (size_t)lm * ldb + lq * 8;
    #pragma unroll 4
    for (int k = 0; k < K; k += 32) {
        const bf16x8 fah = *(const bf16x8*)(ah + k);
        const bf16x8 fal = *(const bf16x8*)(al + k);
        const bf16x8 fbh = *(const bf16x8*)(bh + k);
        const bf16x8 fbl = *(const bf16x8*)(bl + k);
        a1 = __builtin_amdgcn_mfma_f32_16x16x32_bf16(fah, fbh, a1, 0, 0, 0);
        a2 = __builtin_amdgcn_mfma_f32_16x16x32_bf16(fah, fbl, a2, 0, 0, 0);
        a2 = __builtin_amdgcn_mfma_f32_16x16x32_bf16(fal, fbh, a2, 0, 0, 0);
    }
    return a1 + a2;
}

// ws layout (ushort offsets)
#define O_XHI  0u
#define O_XLO  1048576u
#define O_XTHI 2097152u
#define O_XTLO 3145728u
#define O_GHI0 4194304u
#define O_GLO0 4456448u
#define O_GHI1 4718592u
#define O_GLO1 4980736u
#define O_HHI  5242880u
#define O_HLO  5505024u
#define O_BHI0 5767168u
#define O_BLO0 6029312u
#define O_BHI1 6291456u
#define O_BLO1 6553600u
#define O_BTHI 6815744u
#define O_BTLO 7077888u

__global__ __launch_bounds__(256, 2) void ns_fused(
    const float* __restrict__ X, float* __restrict__ out,
    unsigned short* __restrict__ ws) {
    cg::grid_group grid = cg::this_grid();

    unsigned short* Xhi  = ws + O_XHI;
    unsigned short* Xlo  = ws + O_XLO;
    unsigned short* XThi = ws + O_XTHI;
    unsigned short* XTlo = ws + O_XTLO;
    unsigned short* Ghi[2] = {ws + O_GHI0, ws + O_GHI1};
    unsigned short* Glo[2] = {ws + O_GLO0, ws + O_GLO1};
    unsigned short* Hhi  = ws + O_HHI;
    unsigned short* Hlo  = ws + O_HLO;
    unsigned short* Bhi[2] = {ws + O_BHI0, ws + O_BHI1};
    unsigned short* Blo[2] = {ws + O_BLO0, ws + O_BLO1};
    unsigned short* BThi = ws + O_BTHI;
    unsigned short* BTlo = ws + O_BTLO;
    float* P = out;  // 4 x 512^2 fp32 partials overlay d_out exactly (4 MB)

    const int t = threadIdx.x;
    const int tid = blockIdx.x * 256 + t;          // 0..131071
    const int lane = t & 63;
    const int wid = blockIdx.x * 4 + (t >> 6);     // 0..2047
    const int lm = lane & 15, lq = lane >> 4;

    // ---- P0: X -> Xhi/Xlo + XThi/XTlo; B0 = I
    {
        const int base = tid * 8;
        const int row = base >> 9, col = base & (M - 1);
        const float4 v4a = *(const float4*)(X + base);
        const float4 v4b = *(const float4*)(X + base + 4);
        const float v[8] = {v4a.x, v4a.y, v4a.z, v4a.w, v4b.x, v4b.y, v4b.z, v4b.w};
        unsigned short hi[8], lo[8];
        #pragma unroll
        for (int i = 0; i < 8; ++i) { hi[i] = f2bf(v[i]); lo[i] = f2bf(v[i] - bf2f(hi[i])); }
        *(uint4*)(Xhi + base) = pack8(hi);
        *(uint4*)(Xlo + base) = pack8(lo);
        #pragma unroll
        for (int i = 0; i < 8; ++i) {
            XThi[(size_t)(col + i) * D + row] = hi[i];
            XTlo[(size_t)(col + i) * D + row] = lo[i];
        }
        if (tid < M * M / 8) {
            const int b2 = tid * 8;
            const int r2 = b2 >> 9, c2 = b2 & (M - 1);
            unsigned short bi[8];
            #pragma unroll
            for (int i = 0; i < 8; ++i)
                bi[i] = (c2 + i == r2) ? (unsigned short)0x3F80 : (unsigned short)0;
            *(uint4*)(Bhi[0] + b2) = pack8(bi);
            uint4 z; z.x = z.y = z.z = z.w = 0u;
            *(uint4*)(Blo[0] + b2) = z;
        }
    }
    grid.sync();

    // ---- P1: split-K gram partials P[z] = chunk-z of X^T X (4096 units, 2/wave)
    #pragma unroll
    for (int r = 0; r < 2; ++r) {
        const int unit = wid + 2048 * r;
        const int tile = unit >> 2, z = unit & 3;
        const int i0 = (tile >> 5) * 16, j0 = (tile & 31) * 16;
        const size_t ko = (size_t)z * 512;
        const f32x4 g = mm_tile(XThi + (size_t)i0 * D + ko, XTlo + (size_t)i0 * D + ko, D,
                                XThi + (size_t)j0 * D + ko, XTlo + (size_t)j0 * D + ko, D,
                                512, lm, lq);
        float* Pp = P + (size_t)z * M * M + (size_t)(i0 + lq * 4) * M + j0 + lm;
        #pragma unroll
        for (int q = 0; q < 4; ++q) Pp[(size_t)q * M] = g[q];
    }
    grid.sync();

    // ---- P2: G = sum_z P[z] (2 elems/thread)
    {
        const int idx = tid * 2;
        #pragma unroll
        for (int e = 0; e < 2; ++e) {
            const float g = P[idx + e] + P[M * M + idx + e]
                          + P[2 * M * M + idx + e] + P[3 * M * M + idx + e];
            const unsigned short h = f2bf(g);
            Ghi[0][idx + e] = h;
            Glo[0][idx + e] = f2bf(g - bf2f(h));
        }
    }
    grid.sync();

    // ---- steps: H = G^2; B' = 1.5B - 0.5 B·G; G' = 2.25G - 1.5H + 0.25 G·H
    for (int s = 0; s < STEPS; ++s) {
        const int g = s & 1, n = g ^ 1;
        const unsigned short* Gh = Ghi[g];
        const unsigned short* Gl = Glo[g];

        if (wid < 1024) {  // H = G·G
            const int i0 = (wid >> 5) * 16, j0 = (wid & 31) * 16;
            const f32x4 acc = mm_tile(Gh + (size_t)i0 * M, Gl + (size_t)i0 * M, M,
                                      Gh + (size_t)j0 * M, Gl + (size_t)j0 * M, M,
                                      M, lm, lq);
            #pragma unroll
            for (int q = 0; q < 4; ++q) {
                const size_t idx = (size_t)(i0 + lq * 4 + q) * M + j0 + lm;
                const unsigned short h = f2bf(acc[q]);
                Hhi[idx] = h;
                Hlo[idx] = f2bf(acc[q] - bf2f(h));
            }
        } else {           // B' = 1.5B - 0.5 B·G
            const int tl = wid - 1024;
            const int i0 = (tl >> 5) * 16, j0 = (tl & 31) * 16;
            const f32x4 acc = mm_tile(Bhi[g] + (size_t)i0 * M, Blo[g] + (size_t)i0 * M, M,
                                      Gh + (size_t)j0 * M, Gl + (size_t)j0 * M, M,
                                      M, lm, lq);
            #pragma unroll
            for (int q = 0; q < 4; ++q) {
                const size_t idx = (size_t)(i0 + lq * 4 + q) * M + j0 + lm;
                const float bv = bf2f(Bhi[g][idx]) + bf2f(Blo[g][idx]);
                const float nb = 1.5f * bv - 0.5f * acc[q];
                const unsigned short h = f2bf(nb);
                const unsigned short l = f2bf(nb - bf2f(h));
                Bhi[n][idx] = h;
                Blo[n][idx] = l;
                if (s == STEPS - 1) {  // emit transposed for final X·B
                    const size_t tix = (size_t)(j0 + lm) * M + i0 + lq * 4 + q;
                    BThi[tix] = h;
                    BTlo[tix] = l;
                }
            }
        }
        grid.sync();

        if (wid < 1024) {  // G' (skipped on last step: G no longer needed)
            if (s < STEPS - 1) {
                const int i0 = (wid >> 5) * 16, j0 = (wid & 31) * 16;
                const f32x4 acc = mm_tile(Gh + (size_t)i0 * M, Gl + (size_t)i0 * M, M,
                                          Hhi + (size_t)j0 * M, Hlo + (size_t)j0 * M, M,
                                          M, lm, lq);
                #pragma unroll
                for (int q = 0; q < 4; ++q) {
                    const size_t idx = (size_t)(i0 + lq * 4 + q) * M + j0 + lm;
                    const float gv = bf2f(Gh[idx]) + bf2f(Gl[idx]);
                    const float hv = bf2f(Hhi[idx]) + bf2f(Hlo[idx]);
                    const float ng = 2.25f * gv - 1.5f * hv + 0.25f * acc[q];
                    const unsigned short h = f2bf(ng);
                    Ghi[n][idx] = h;
                    Glo[n][idx] = f2bf(ng - bf2f(h));
                }
            }
        }
        grid.sync();
    }

    // ---- Pd: out = X·B (4096 tiles, 2/wave)
    #pragma unroll
    for (int r = 0; r < 2; ++r) {
        const int tile = wid + 2048 * r;
        const int i0 = (tile >> 5) * 16, j0 = (tile & 31) * 16;
        const f32x4 acc = mm_tile(Xhi + (size_t)i0 * M, Xlo + (size_t)i0 * M, M,
                                  BThi + (size_t)j0 * M, BTlo + (size_t)j0 * M, M,
                                  M, lm, lq);
        float* o = out + (size_t)(i0 + lq * 4) * M + j0 + lm;
        #pragma unroll
        for (int q = 0; q < 4; ++q) o[(size_t)q * M] = acc[q];
    }
}

extern "C" void kernel_launch(void* const* d_in, const int* in_sizes, int n_in,
                              void* d_out, int out_size, void* d_ws, size_t ws_size,
                              hipStream_t stream) {
    const float* Xin = (const float*)d_in[0];
    float* out = (float*)d_out;
    unsigned short* ws = (unsigned short*)d_ws;
    void* args[] = {(void*)&Xin, (void*)&out, (void*)&ws};
    hipLaunchCooperativeKernel((void*)ns_fused, dim3(NBLK), dim3(256), args, 0, stream);
}

// Round 7
// 254.834 us; speedup vs baseline: 5.6323x; 5.6323x over previous
//
#include <hip/hip_runtime.h>

#define D 2048
#define M 512

typedef __attribute__((ext_vector_type(8))) short bf16x8;
typedef __attribute__((ext_vector_type(4))) float f32x4;

// Tuned Newton-Schulz coefficients (equioscillation on sv interval [0.4,1.6]):
// step1 maps [0.4,1.6]->[0.70,1.30]; step2 ->[0.93,1.07]; steps 3-5 standard.
#define CA1 1.8409358f
#define CB1 0.54790666f
#define CA2 1.5803828f
#define CB2 0.51145935f

__device__ inline unsigned short f2bf(float f) {
    union { float f; unsigned u; } v; v.f = f;
    unsigned r = v.u + 0x7fffu + ((v.u >> 16) & 1u);  // RNE
    return (unsigned short)(r >> 16);
}
__device__ inline float bf2f(unsigned short h) {
    union { float f; unsigned u; } v; v.u = ((unsigned)h) << 16;
    return v.f;
}
__device__ inline uint2 pack4(const unsigned short* h) {
    uint2 u;
    u.x = h[0] | ((unsigned)h[1] << 16);
    u.y = h[2] | ((unsigned)h[3] << 16);
    return u;
}
__device__ inline uint4 pack8(const unsigned short* h) {
    uint4 u;
    u.x = h[0] | ((unsigned)h[1] << 16);
    u.y = h[2] | ((unsigned)h[3] << 16);
    u.z = h[4] | ((unsigned)h[5] << 16);
    u.w = h[6] | ((unsigned)h[7] << 16);
    return u;
}

// 16x16 tile of U·V in split-bf16, direct global->register fragments.
// aHi/aLo: U rows (pre-offset to row block). bHi/bLo: V^T rows (V symmetric
// => V row-major works). K multiple of 32.
__device__ inline f32x4 mm_tile(const unsigned short* __restrict__ aHi,
                                const unsigned short* __restrict__ aLo, int lda,
                                const unsigned short* __restrict__ bHi,
                                const unsigned short* __restrict__ bLo, int ldb,
                                int K, int lm, int lq) {
    f32x4 a1 = {0.f, 0.f, 0.f, 0.f}, a2 = {0.f, 0.f, 0.f, 0.f};
    const unsigned short* ah = aHi + (size_t)lm * lda + lq * 8;
    const unsigned short* al = aLo + (size_t)lm * lda + lq * 8;
    const unsigned short* bh = bHi + (size_t)lm * ldb + lq * 8;
    const unsigned short* bl = bLo + (size_t)lm * ldb + lq * 8;
    #pragma unroll 4
    for (int k = 0; k < K; k += 32) {
        const bf16x8 fah = *(const bf16x8*)(ah + k);
        const bf16x8 fal = *(const bf16x8*)(al + k);
        const bf16x8 fbh = *(const bf16x8*)(bh + k);
        const bf16x8 fbl = *(const bf16x8*)(bl + k);
        a1 = __builtin_amdgcn_mfma_f32_16x16x32_bf16(fah, fbh, a1, 0, 0, 0);
        a2 = __builtin_amdgcn_mfma_f32_16x16x32_bf16(fah, fbl, a2, 0, 0, 0);
        a2 = __builtin_amdgcn_mfma_f32_16x16x32_bf16(fal, fbh, a2, 0, 0, 0);
    }
    return a1 + a2;
}

// X fp32 (D x M) -> hi/lo bf16 row-major + transposed hi/lo (M x D)
__global__ __launch_bounds__(256) void init_split(
    const float* __restrict__ X,
    unsigned short* __restrict__ Xhi, unsigned short* __restrict__ Xlo,
    unsigned short* __restrict__ XThi, unsigned short* __restrict__ XTlo) {
    const int t = blockIdx.x * 256 + threadIdx.x;
    const int base = t * 8;
    const int row = base >> 9;
    const int col = base & (M - 1);
    const float4 a = *(const float4*)(X + base);
    const float4 b = *(const float4*)(X + base + 4);
    const float v[8] = {a.x, a.y, a.z, a.w, b.x, b.y, b.z, b.w};
    unsigned short hi[8], lo[8];
    #pragma unroll
    for (int i = 0; i < 8; ++i) { hi[i] = f2bf(v[i]); lo[i] = f2bf(v[i] - bf2f(hi[i])); }
    *(uint4*)(Xhi + base) = pack8(hi);
    *(uint4*)(Xlo + base) = pack8(lo);
    #pragma unroll
    for (int i = 0; i < 8; ++i) {
        XThi[(size_t)(col + i) * D + row] = hi[i];
        XTlo[(size_t)(col + i) * D + row] = lo[i];
    }
}

// Split-K=4 gram partials: P[z] = chunk-z of X^T X. 4096 one-wave blocks.
__global__ __launch_bounds__(64) void gram_partial(
    const unsigned short* __restrict__ XThi, const unsigned short* __restrict__ XTlo,
    float* __restrict__ P) {
    const int wid = blockIdx.x;
    const int lane = threadIdx.x;
    const int lm = lane & 15, lq = lane >> 4;
    const int tile = wid >> 2, z = wid & 3;
    const int i0 = (tile >> 5) * 16, j0 = (tile & 31) * 16;
    const size_t ko = (size_t)z * 512;
    const f32x4 g = mm_tile(XThi + (size_t)i0 * D + ko, XTlo + (size_t)i0 * D + ko, D,
                            XThi + (size_t)j0 * D + ko, XTlo + (size_t)j0 * D + ko, D,
                            512, lm, lq);
    float* Pp = P + (size_t)z * M * M + (size_t)(i0 + lq * 4) * M + j0 + lm;
    #pragma unroll
    for (int q = 0; q < 4; ++q) Pp[(size_t)q * M] = g[q];
}

// G0 = sum_z P[z]; B1 = CA1*I - CB1*G0. Both emitted hi/lo bf16.
__global__ __launch_bounds__(256) void reduce_g(
    const float* __restrict__ P,
    unsigned short* __restrict__ Ghi, unsigned short* __restrict__ Glo,
    unsigned short* __restrict__ Bhi, unsigned short* __restrict__ Blo) {
    const int idx = (blockIdx.x * 256 + threadIdx.x) * 4;
    const int i = idx >> 9, j = idx & (M - 1);
    unsigned short gh[4], gl[4], bh[4], bl[4];
    #pragma unroll
    for (int e = 0; e < 4; ++e) {
        const float g = P[idx + e] + P[M * M + idx + e]
                      + P[2 * M * M + idx + e] + P[3 * M * M + idx + e];
        gh[e] = f2bf(g); gl[e] = f2bf(g - bf2f(gh[e]));
        const float b = ((j + e) == i ? CA1 : 0.0f) - CB1 * g;
        bh[e] = f2bf(b); bl[e] = f2bf(b - bf2f(bh[e]));
    }
    *(uint2*)(Ghi + idx) = pack4(gh);
    *(uint2*)(Glo + idx) = pack4(gl);
    *(uint2*)(Bhi + idx) = pack4(bh);
    *(uint2*)(Blo + idx) = pack4(bl);
}

// Phase A: first nH one-wave blocks compute H = G·G; remaining nB blocks
// compute B' = a*B - b*(B·G). One wave per 16x16 tile.
__global__ __launch_bounds__(64) void step_a(
    const unsigned short* __restrict__ Gh, const unsigned short* __restrict__ Gl,
    const unsigned short* __restrict__ Bh, const unsigned short* __restrict__ Bl,
    unsigned short* __restrict__ Hh, unsigned short* __restrict__ Hl,
    unsigned short* __restrict__ Bnh, unsigned short* __restrict__ Bnl,
    const float a, const float b, const int nH) {
    const int wid = blockIdx.x;
    const int lane = threadIdx.x;
    const int lm = lane & 15, lq = lane >> 4;
    if (wid < nH) {
        const int i0 = (wid >> 5) * 16, j0 = (wid & 31) * 16;
        const f32x4 acc = mm_tile(Gh + (size_t)i0 * M, Gl + (size_t)i0 * M, M,
                                  Gh + (size_t)j0 * M, Gl + (size_t)j0 * M, M,
                                  M, lm, lq);
        #pragma unroll
        for (int q = 0; q < 4; ++q) {
            const size_t idx = (size_t)(i0 + lq * 4 + q) * M + j0 + lm;
            const unsigned short h = f2bf(acc[q]);
            Hh[idx] = h;
            Hl[idx] = f2bf(acc[q] - bf2f(h));
        }
    } else {
        const int tl = wid - nH;
        const int i0 = (tl >> 5) * 16, j0 = (tl & 31) * 16;
        const f32x4 acc = mm_tile(Bh + (size_t)i0 * M, Bl + (size_t)i0 * M, M,
                                  Gh + (size_t)j0 * M, Gl + (size_t)j0 * M, M,
                                  M, lm, lq);
        #pragma unroll
        for (int q = 0; q < 4; ++q) {
            const size_t idx = (size_t)(i0 + lq * 4 + q) * M + j0 + lm;
            const float bv = bf2f(Bh[idx]) + bf2f(Bl[idx]);
            const float nb = a * bv - b * acc[q];
            const unsigned short h = f2bf(nb);
            Bnh[idx] = h;
            Bnl[idx] = f2bf(nb - bf2f(h));
        }
    }
}

// Phase B: G' = a^2 G - 2ab H + b^2 (G·H). 1024 one-wave blocks.
__global__ __launch_bounds__(64) void step_b(
    const unsigned short* __restrict__ Gh, const unsigned short* __restrict__ Gl,
    const unsigned short* __restrict__ Hh, const unsigned short* __restrict__ Hl,
    unsigned short* __restrict__ Gnh, unsigned short* __restrict__ Gnl,
    const float a, const float b) {
    const int wid = blockIdx.x;
    const int lane = threadIdx.x;
    const int lm = lane & 15, lq = lane >> 4;
    const int i0 = (wid >> 5) * 16, j0 = (wid & 31) * 16;
    const f32x4 acc = mm_tile(Gh + (size_t)i0 * M, Gl + (size_t)i0 * M, M,
                              Hh + (size_t)j0 * M, Hl + (size_t)j0 * M, M,
                              M, lm, lq);
    const float aa = a * a, ab2 = 2.0f * a * b, bb = b * b;
    #pragma unroll
    for (int q = 0; q < 4; ++q) {
        const size_t idx = (size_t)(i0 + lq * 4 + q) * M + j0 + lm;
        const float gv = bf2f(Gh[idx]) + bf2f(Gl[idx]);
        const float hv = bf2f(Hh[idx]) + bf2f(Hl[idx]);
        const float ng = aa * gv - ab2 * hv + bb * acc[q];
        const unsigned short h = f2bf(ng);
        Gnh[idx] = h;
        Gnl[idx] = f2bf(ng - bf2f(h));
    }
}

// out = X·B (B symmetric). 4096 one-wave blocks.
__global__ __launch_bounds__(64) void final_mm(
    const unsigned short* __restrict__ Xhi, const unsigned short* __restrict__ Xlo,
    const unsigned short* __restrict__ Bh, const unsigned short* __restrict__ Bl,
    float* __restrict__ out) {
    const int wid = blockIdx.x;
    const int lane = threadIdx.x;
    const int lm = lane & 15, lq = lane >> 4;
    const int i0 = (wid >> 5) * 16, j0 = (wid & 31) * 16;
    const f32x4 acc = mm_tile(Xhi + (size_t)i0 * M, Xlo + (size_t)i0 * M, M,
                              Bh + (size_t)j0 * M, Bl + (size_t)j0 * M, M,
                              M, lm, lq);
    float* o = out + (size_t)(i0 + lq * 4) * M + j0 + lm;
    #pragma unroll
    for (int q = 0; q < 4; ++q) o[(size_t)q * M] = acc[q];
}

extern "C" void kernel_launch(void* const* d_in, const int* in_sizes, int n_in,
                              void* d_out, int out_size, void* d_ws, size_t ws_size,
                              hipStream_t stream) {
    const float* Xin = (const float*)d_in[0];
    float* out = (float*)d_out;
    unsigned short* w = (unsigned short*)d_ws;

    unsigned short* Xhi  = w;                       // 1048576 each
    unsigned short* Xlo  = w + 1048576u;
    unsigned short* XThi = w + 2097152u;
    unsigned short* XTlo = w + 3145728u;
    unsigned short* Gh[2] = {w + 4194304u, w + 4718592u};   // 262144 each
    unsigned short* Gl[2] = {w + 4456448u, w + 4980736u};
    unsigned short* Hh = w + 5242880u;
    unsigned short* Hl = w + 5505024u;
    unsigned short* Bh[2] = {w + 5767168u, w + 6291456u};
    unsigned short* Bl[2] = {w + 6029312u, w + 6553600u};
    float* P = out;  // 4 x 512^2 fp32 partials overlay d_out exactly

    // 1-3: prep
    init_split<<<512, 256, 0, stream>>>(Xin, Xhi, Xlo, XThi, XTlo);
    gram_partial<<<4096, 64, 0, stream>>>(XThi, XTlo, P);
    reduce_g<<<256, 256, 0, stream>>>(P, Gh[0], Gl[0], Bh[0], Bl[0]);  // G0, B1

    // step 1: H = G0^2 ; G1 = CA1^2 G0 - 2 CA1 CB1 H + CB1^2 G0 H
    step_a<<<1024, 64, 0, stream>>>(Gh[0], Gl[0], nullptr, nullptr,
                                    Hh, Hl, nullptr, nullptr, 0.f, 0.f, 1024);
    step_b<<<1024, 64, 0, stream>>>(Gh[0], Gl[0], Hh, Hl, Gh[1], Gl[1], CA1, CB1);
    // step 2: H = G1^2 || B2 = CA2 B1 - CB2 B1 G1 ; G2
    step_a<<<2048, 64, 0, stream>>>(Gh[1], Gl[1], Bh[0], Bl[0],
                                    Hh, Hl, Bh[1], Bl[1], CA2, CB2, 1024);
    step_b<<<1024, 64, 0, stream>>>(Gh[1], Gl[1], Hh, Hl, Gh[0], Gl[0], CA2, CB2);
    // step 3 (standard): B3 ; G3
    step_a<<<2048, 64, 0, stream>>>(Gh[0], Gl[0], Bh[1], Bl[1],
                                    Hh, Hl, Bh[0], Bl[0], 1.5f, 0.5f, 1024);
    step_b<<<1024, 64, 0, stream>>>(Gh[0], Gl[0], Hh, Hl, Gh[1], Gl[1], 1.5f, 0.5f);
    // step 4: B4 ; G4
    step_a<<<2048, 64, 0, stream>>>(Gh[1], Gl[1], Bh[0], Bl[0],
                                    Hh, Hl, Bh[1], Bl[1], 1.5f, 0.5f, 1024);
    step_b<<<1024, 64, 0, stream>>>(Gh[1], Gl[1], Hh, Hl, Gh[0], Gl[0], 1.5f, 0.5f);
    // step 5: B5 only
    step_a<<<1024, 64, 0, stream>>>(Gh[0], Gl[0], Bh[1], Bl[1],
                                    Hh, Hl, Bh[0], Bl[0], 1.5f, 0.5f, 0);
    // out = X · B5
    final_mm<<<4096, 64, 0, stream>>>(Xhi, Xlo, Bh[0], Bl[0], out);
}

// Round 8
// 219.693 us; speedup vs baseline: 6.5333x; 1.1600x over previous
//
#include <hip/hip_runtime.h>

#define D 2048
#define M 512

// Tuned NS coefficients: [0.4,1.6] -> [0.70,1.30] -> [0.931,1.069] -> 7.3e-3 -> 8.1e-5
#define CA1 1.8409358f
#define CB1 0.54790666f
#define CA2 1.5803828f
#define CB2 0.51145935f
#define CA3 1.5f
#define CB3 0.5f
#define CA4 1.5f
#define CB4 0.5f

typedef __attribute__((ext_vector_type(8))) short bf16x8;
typedef __attribute__((ext_vector_type(4))) float f32x4;

__device__ inline unsigned short f2bf(float f) {
    union { float f; unsigned u; } v; v.f = f;
    unsigned r = v.u + 0x7fffu + ((v.u >> 16) & 1u);  // RNE
    return (unsigned short)(r >> 16);
}
__device__ inline float bf2f(unsigned short h) {
    union { float f; unsigned u; } v; v.u = ((unsigned)h) << 16;
    return v.f;
}
__device__ inline uint4 pack8(const unsigned short* h) {
    uint4 u;
    u.x = h[0] | ((unsigned)h[1] << 16);
    u.y = h[2] | ((unsigned)h[3] << 16);
    u.z = h[4] | ((unsigned)h[5] << 16);
    u.w = h[6] | ((unsigned)h[7] << 16);
    return u;
}

// 16x16 tile of U·V in split-bf16, direct global->register fragments.
// aHi/aLo: U rows (pre-offset). bHi/bLo: V^T rows (all V here symmetric =>
// row-major V works). K multiple of 32.
__device__ inline f32x4 mm_tile(const unsigned short* __restrict__ aHi,
                                const unsigned short* __restrict__ aLo, int lda,
                                const unsigned short* __restrict__ bHi,
                                const unsigned short* __restrict__ bLo, int ldb,
                                int K, int lm, int lq) {
    f32x4 a1 = {0.f, 0.f, 0.f, 0.f}, a2 = {0.f, 0.f, 0.f, 0.f};
    const unsigned short* ah = aHi + (size_t)lm * lda + lq * 8;
    const unsigned short* al = aLo + (size_t)lm * lda + lq * 8;
    const unsigned short* bh = bHi + (size_t)lm * ldb + lq * 8;
    const unsigned short* bl = bLo + (size_t)lm * ldb + lq * 8;
    #pragma unroll 4
    for (int k = 0; k < K; k += 32) {
        const bf16x8 fah = *(const bf16x8*)(ah + k);
        const bf16x8 fal = *(const bf16x8*)(al + k);
        const bf16x8 fbh = *(const bf16x8*)(bh + k);
        const bf16x8 fbl = *(const bf16x8*)(bl + k);
        a1 = __builtin_amdgcn_mfma_f32_16x16x32_bf16(fah, fbh, a1, 0, 0, 0);
        a2 = __builtin_amdgcn_mfma_f32_16x16x32_bf16(fah, fbl, a2, 0, 0, 0);
        a2 = __builtin_amdgcn_mfma_f32_16x16x32_bf16(fal, fbh, a2, 0, 0, 0);
    }
    return a1 + a2;
}

// X fp32 (D x M) -> hi/lo bf16 row-major + transposed hi/lo (M x D)
__global__ __launch_bounds__(256) void init_split(
    const float* __restrict__ X,
    unsigned short* __restrict__ Xhi, unsigned short* __restrict__ Xlo,
    unsigned short* __restrict__ XThi, unsigned short* __restrict__ XTlo) {
    const int t = blockIdx.x * 256 + threadIdx.x;
    const int base = t * 8;
    const int row = base >> 9;
    const int col = base & (M - 1);
    const float4 a = *(const float4*)(X + base);
    const float4 b = *(const float4*)(X + base + 4);
    const float v[8] = {a.x, a.y, a.z, a.w, b.x, b.y, b.z, b.w};
    unsigned short hi[8], lo[8];
    #pragma unroll
    for (int i = 0; i < 8; ++i) { hi[i] = f2bf(v[i]); lo[i] = f2bf(v[i] - bf2f(hi[i])); }
    *(uint4*)(Xhi + base) = pack8(hi);
    *(uint4*)(Xlo + base) = pack8(lo);
    #pragma unroll
    for (int i = 0; i < 8; ++i) {
        XThi[(size_t)(col + i) * D + row] = hi[i];
        XTlo[(size_t)(col + i) * D + row] = lo[i];
    }
}

// G0 = X^T X (K=2048, no split) + C1 = CA1*I - CB1*G0. 1024 tiles, 256 blocks.
__global__ __launch_bounds__(256) void gram_c(
    const unsigned short* __restrict__ XThi, const unsigned short* __restrict__ XTlo,
    unsigned short* __restrict__ Gh, unsigned short* __restrict__ Gl,
    unsigned short* __restrict__ Ch, unsigned short* __restrict__ Cl) {
    const int t = threadIdx.x;
    const int wid = blockIdx.x * 4 + (t >> 6);
    const int lane = t & 63;
    const int lm = lane & 15, lq = lane >> 4;
    const int i0 = (wid >> 5) * 16, j0 = (wid & 31) * 16;
    const f32x4 g = mm_tile(XThi + (size_t)i0 * D, XTlo + (size_t)i0 * D, D,
                            XThi + (size_t)j0 * D, XTlo + (size_t)j0 * D, D,
                            D, lm, lq);
    #pragma unroll
    for (int q = 0; q < 4; ++q) {
        const int row = i0 + lq * 4 + q, col = j0 + lm;
        const size_t idx = (size_t)row * M + col;
        const float gv = g[q];
        unsigned short h = f2bf(gv);
        Gh[idx] = h; Gl[idx] = f2bf(gv - bf2f(h));
        const float c = (row == col ? CA1 : 0.0f) - CB1 * gv;
        h = f2bf(c);
        Ch[idx] = h; Cl[idx] = f2bf(c - bf2f(h));
    }
}

// 1-2 independent matmul jobs: O = U·V, split-bf16 out. 1024 tiles/job.
__global__ __launch_bounds__(256) void mm2(
    const unsigned short* __restrict__ U0h, const unsigned short* __restrict__ U0l,
    const unsigned short* __restrict__ V0h, const unsigned short* __restrict__ V0l,
    unsigned short* __restrict__ O0h, unsigned short* __restrict__ O0l,
    const unsigned short* __restrict__ U1h, const unsigned short* __restrict__ U1l,
    const unsigned short* __restrict__ V1h, const unsigned short* __restrict__ V1l,
    unsigned short* __restrict__ O1h, unsigned short* __restrict__ O1l) {
    const int t = threadIdx.x;
    const int unit = blockIdx.x * 4 + (t >> 6);
    const int lane = t & 63;
    const int lm = lane & 15, lq = lane >> 4;
    const int job = unit >> 10;
    const int tl = unit & 1023;
    const unsigned short* Uh = job ? U1h : U0h;
    const unsigned short* Ul = job ? U1l : U0l;
    const unsigned short* Vh = job ? V1h : V0h;
    const unsigned short* Vl = job ? V1l : V0l;
    unsigned short* Oh = job ? O1h : O0h;
    unsigned short* Ol = job ? O1l : O0l;
    const int i0 = (tl >> 5) * 16, j0 = (tl & 31) * 16;
    const f32x4 acc = mm_tile(Uh + (size_t)i0 * M, Ul + (size_t)i0 * M, M,
                              Vh + (size_t)j0 * M, Vl + (size_t)j0 * M, M,
                              M, lm, lq);
    #pragma unroll
    for (int q = 0; q < 4; ++q) {
        const size_t idx = (size_t)(i0 + lq * 4 + q) * M + j0 + lm;
        const unsigned short h = f2bf(acc[q]);
        Oh[idx] = h;
        Ol[idx] = f2bf(acc[q] - bf2f(h));
    }
}

// W = U·V; optionally store G=W; always store C = a*I - b*W. 1024 tiles.
__global__ __launch_bounds__(256) void mm_g(
    const unsigned short* __restrict__ Uh, const unsigned short* __restrict__ Ul,
    const unsigned short* __restrict__ Vh, const unsigned short* __restrict__ Vl,
    unsigned short* __restrict__ Gh, unsigned short* __restrict__ Gl,
    unsigned short* __restrict__ Ch, unsigned short* __restrict__ Cl,
    const float a, const float b, const int writeG) {
    const int t = threadIdx.x;
    const int wid = blockIdx.x * 4 + (t >> 6);
    const int lane = t & 63;
    const int lm = lane & 15, lq = lane >> 4;
    const int i0 = (wid >> 5) * 16, j0 = (wid & 31) * 16;
    const f32x4 acc = mm_tile(Uh + (size_t)i0 * M, Ul + (size_t)i0 * M, M,
                              Vh + (size_t)j0 * M, Vl + (size_t)j0 * M, M,
                              M, lm, lq);
    #pragma unroll
    for (int q = 0; q < 4; ++q) {
        const int row = i0 + lq * 4 + q, col = j0 + lm;
        const size_t idx = (size_t)row * M + col;
        const float w = acc[q];
        if (writeG) {
            const unsigned short h = f2bf(w);
            Gh[idx] = h; Gl[idx] = f2bf(w - bf2f(h));
        }
        const float c = (row == col ? a : 0.0f) - b * w;
        const unsigned short h2 = f2bf(c);
        Ch[idx] = h2; Cl[idx] = f2bf(c - bf2f(h2));
    }
}

// out = X·B (B symmetric). 4096 tiles, 1024 blocks.
__global__ __launch_bounds__(256) void final_mm(
    const unsigned short* __restrict__ Xhi, const unsigned short* __restrict__ Xlo,
    const unsigned short* __restrict__ Bh, const unsigned short* __restrict__ Bl,
    float* __restrict__ out) {
    const int t = threadIdx.x;
    const int tile = blockIdx.x * 4 + (t >> 6);   // 0..4095 (128 x 32)
    const int lane = t & 63;
    const int lm = lane & 15, lq = lane >> 4;
    const int i0 = (tile >> 5) * 16, j0 = (tile & 31) * 16;
    const f32x4 acc = mm_tile(Xhi + (size_t)i0 * M, Xlo + (size_t)i0 * M, M,
                              Bh + (size_t)j0 * M, Bl + (size_t)j0 * M, M,
                              M, lm, lq);
    float* o = out + (size_t)(i0 + lq * 4) * M + j0 + lm;
    #pragma unroll
    for (int q = 0; q < 4; ++q) o[(size_t)q * M] = acc[q];
}

extern "C" void kernel_launch(void* const* d_in, const int* in_sizes, int n_in,
                              void* d_out, int out_size, void* d_ws, size_t ws_size,
                              hipStream_t stream) {
    const float* Xin = (const float*)d_in[0];
    float* out = (float*)d_out;
    unsigned short* w = (unsigned short*)d_ws;

    unsigned short* Xhi  = w;
    unsigned short* Xlo  = w + 1048576u;
    unsigned short* XThi = w + 2097152u;
    unsigned short* XTlo = w + 3145728u;
    unsigned short* Gh   = w + 4194304u;
    unsigned short* Gl   = w + 4456448u;
    unsigned short* Th   = w + 4718592u;
    unsigned short* Tl   = w + 4980736u;
    unsigned short* C0h  = w + 5242880u;
    unsigned short* C0l  = w + 5505024u;
    unsigned short* C1h  = w + 5767168u;
    unsigned short* C1l  = w + 6029312u;
    unsigned short* B0h  = w + 6291456u;
    unsigned short* B0l  = w + 6553600u;
    unsigned short* B1h  = w + 6815744u;
    unsigned short* B1l  = w + 7077888u;

    // 1: bf16 hi/lo split of X and X^T
    init_split<<<512, 256, 0, stream>>>(Xin, Xhi, Xlo, XThi, XTlo);
    // 2: G0 = X^T X ; C1 (=B1) = CA1 I - CB1 G0
    gram_c<<<256, 256, 0, stream>>>(XThi, XTlo, Gh, Gl, C0h, C0l);
    // 3: T1 = B1·G0
    mm2<<<256, 256, 0, stream>>>(C0h, C0l, Gh, Gl, Th, Tl,
                                 nullptr, nullptr, nullptr, nullptr, nullptr, nullptr);
    // 4: G1 = B1·T1 ; C2 = CA2 I - CB2 G1
    mm_g<<<256, 256, 0, stream>>>(C0h, C0l, Th, Tl, Gh, Gl, C1h, C1l, CA2, CB2, 1);
    // 5: T2 = C2·G1  ||  B2 = B1·C2
    mm2<<<512, 256, 0, stream>>>(C1h, C1l, Gh, Gl, Th, Tl,
                                 C0h, C0l, C1h, C1l, B0h, B0l);
    // 6: G2 = C2·T2 ; C3 = CA3 I - CB3 G2
    mm_g<<<256, 256, 0, stream>>>(C1h, C1l, Th, Tl, Gh, Gl, C0h, C0l, CA3, CB3, 1);
    // 7: T3 = C3·G2  ||  B3 = B2·C3
    mm2<<<512, 256, 0, stream>>>(C0h, C0l, Gh, Gl, Th, Tl,
                                 B0h, B0l, C0h, C0l, B1h, B1l);
    // 8: C4 = CA4 I - CB4 (C3·T3)   (G3 itself not needed)
    mm_g<<<256, 256, 0, stream>>>(C0h, C0l, Th, Tl, Gh, Gl, C1h, C1l, CA4, CB4, 0);
    // 9: B4 = B3·C4
    mm2<<<256, 256, 0, stream>>>(B1h, B1l, C1h, C1l, B0h, B0l,
                                 nullptr, nullptr, nullptr, nullptr, nullptr, nullptr);
    // 10: out = X·B4
    final_mm<<<1024, 256, 0, stream>>>(Xhi, Xlo, B0h, B0l, out);
}

// Round 9
// 172.885 us; speedup vs baseline: 8.3022x; 1.2707x over previous
//
#include <hip/hip_runtime.h>

#define D 2048
#define M 512

// Tuned NS coefficients, equioscillation on sv interval [0.48,1.52]:
// step1 -> delta 0.2188, step2 -> 0.03633, step3 -> 0.00099
#define CA1 1.7509363f
#define CB1 0.5353890f
#define CA2 1.5424421f
#define CB2 0.5060067f
#define CA3 1.5011558f
#define CB3 0.5001653f

typedef __attribute__((ext_vector_type(8))) short bf16x8;
typedef __attribute__((ext_vector_type(4))) float f32x4;

__device__ inline unsigned short f2bf(float f) {
    union { float f; unsigned u; } v; v.f = f;
    unsigned r = v.u + 0x7fffu + ((v.u >> 16) & 1u);  // RNE
    return (unsigned short)(r >> 16);
}
__device__ inline float bf2f(unsigned short h) {
    union { float f; unsigned u; } v; v.u = ((unsigned)h) << 16;
    return v.f;
}
__device__ inline uint2 pack4(const unsigned short* h) {
    uint2 u;
    u.x = h[0] | ((unsigned)h[1] << 16);
    u.y = h[2] | ((unsigned)h[3] << 16);
    return u;
}

// ---- full-K (per-wave K-range) fragment MACs into acc pair ----
__device__ inline void mm_ks(const unsigned short* __restrict__ aHi,
                             const unsigned short* __restrict__ aLo, int lda,
                             const unsigned short* __restrict__ bHi,
                             const unsigned short* __restrict__ bLo, int ldb,
                             int K, int lm, int lq, f32x4& a1, f32x4& a2) {
    const unsigned short* ah = aHi + (size_t)lm * lda + lq * 8;
    const unsigned short* al = aLo + (size_t)lm * lda + lq * 8;
    const unsigned short* bh = bHi + (size_t)lm * ldb + lq * 8;
    const unsigned short* bl = bLo + (size_t)lm * ldb + lq * 8;
    #pragma unroll 4
    for (int k = 0; k < K; k += 32) {
        const bf16x8 fah = *(const bf16x8*)(ah + k);
        const bf16x8 fal = *(const bf16x8*)(al + k);
        const bf16x8 fbh = *(const bf16x8*)(bh + k);
        const bf16x8 fbl = *(const bf16x8*)(bl + k);
        a1 = __builtin_amdgcn_mfma_f32_16x16x32_bf16(fah, fbh, a1, 0, 0, 0);
        a2 = __builtin_amdgcn_mfma_f32_16x16x32_bf16(fah, fbl, a2, 0, 0, 0);
        a2 = __builtin_amdgcn_mfma_f32_16x16x32_bf16(fal, fbh, a2, 0, 0, 0);
    }
}

// 4-wave split-K reduce: each wave deposits its 16x16 fp32 tile, 256 threads
// return the summed element for (row=t>>4, col=t&15). red must be float[1024].
__device__ inline float splitk_reduce(float* red, const f32x4& s,
                                      int w, int lm, int lq, int t) {
    #pragma unroll
    for (int r = 0; r < 4; ++r) red[w * 256 + (lq * 4 + r) * 16 + lm] = s[r];
    __syncthreads();
    return red[t] + red[256 + t] + red[512 + t] + red[768 + t];
}

// ---- d1: X fp32 (D x M) -> Xhi/Xlo (row-major) + XThi/XTlo (M x D), LDS-tiled
__global__ __launch_bounds__(256) void trans_split(
    const float* __restrict__ X,
    unsigned short* __restrict__ Xhi, unsigned short* __restrict__ Xlo,
    unsigned short* __restrict__ XThi, unsigned short* __restrict__ XTlo) {
    __shared__ unsigned short Lh[64 * 72], Ll[64 * 72];
    const int dBase = blockIdx.x * 64;   // over D (32 blocks)
    const int mBase = blockIdx.y * 64;   // over M (8 blocks)
    const int t = threadIdx.x;
    const int dl = t >> 4;          // 0..15
    const int ml = (t & 15) * 4;    // 0..60
    #pragma unroll
    for (int i = 0; i < 4; ++i) {
        const int d = i * 16 + dl;
        const float4 v4 = *(const float4*)(X + (size_t)(dBase + d) * M + mBase + ml);
        const float v[4] = {v4.x, v4.y, v4.z, v4.w};
        unsigned short hi[4], lo[4];
        #pragma unroll
        for (int j = 0; j < 4; ++j) { hi[j] = f2bf(v[j]); lo[j] = f2bf(v[j] - bf2f(hi[j])); }
        *(uint2*)(Xhi + (size_t)(dBase + d) * M + mBase + ml) = pack4(hi);
        *(uint2*)(Xlo + (size_t)(dBase + d) * M + mBase + ml) = pack4(lo);
        #pragma unroll
        for (int j = 0; j < 4; ++j) { Lh[(ml + j) * 72 + d] = hi[j]; Ll[(ml + j) * 72 + d] = lo[j]; }
    }
    __syncthreads();
    const int m = t >> 2;           // 0..63
    const int dd = (t & 3) * 16;    // 0,16,32,48
    const uint4 h0 = *(const uint4*)(Lh + m * 72 + dd);
    const uint4 h1 = *(const uint4*)(Lh + m * 72 + dd + 8);
    const uint4 l0 = *(const uint4*)(Ll + m * 72 + dd);
    const uint4 l1 = *(const uint4*)(Ll + m * 72 + dd + 8);
    unsigned short* th = XThi + (size_t)(mBase + m) * D + dBase + dd;
    unsigned short* tl = XTlo + (size_t)(mBase + m) * D + dBase + dd;
    *(uint4*)th = h0; *(uint4*)(th + 8) = h1;
    *(uint4*)tl = l0; *(uint4*)(tl + 8) = l1;
}

// ---- d2: G0 = X^T X (block per 16x16 tile, 4-wave split-K over 2048);
//          emit G0 hi/lo and C1 = CA1*I - CB1*G0 hi/lo.
__global__ __launch_bounds__(256) void gram_c(
    const unsigned short* __restrict__ XThi, const unsigned short* __restrict__ XTlo,
    unsigned short* __restrict__ Gh, unsigned short* __restrict__ Gl,
    unsigned short* __restrict__ Ch, unsigned short* __restrict__ Cl) {
    __shared__ float red[1024];
    const int tile = blockIdx.x;
    const int i0 = (tile >> 5) * 16, j0 = (tile & 31) * 16;
    const int t = threadIdx.x, w = t >> 6, lane = t & 63;
    const int lm = lane & 15, lq = lane >> 4;
    const size_t ko = (size_t)w * 512;
    f32x4 a1 = {0.f, 0.f, 0.f, 0.f}, a2 = {0.f, 0.f, 0.f, 0.f};
    mm_ks(XThi + (size_t)i0 * D + ko, XTlo + (size_t)i0 * D + ko, D,
          XThi + (size_t)j0 * D + ko, XTlo + (size_t)j0 * D + ko, D,
          512, lm, lq, a1, a2);
    const float g = splitk_reduce(red, a1 + a2, w, lm, lq, t);
    const int row = i0 + (t >> 4), col = j0 + (t & 15);
    const size_t idx = (size_t)row * M + col;
    unsigned short h = f2bf(g);
    Gh[idx] = h; Gl[idx] = f2bf(g - bf2f(h));
    const float c = (row == col ? CA1 : 0.0f) - CB1 * g;
    h = f2bf(c);
    Ch[idx] = h; Cl[idx] = f2bf(c - bf2f(h));
}

// ---- plain small mm: O = U·V (V symmetric). Block per tile, split-K=4.
__global__ __launch_bounds__(256) void mm_small(
    const unsigned short* __restrict__ Uh, const unsigned short* __restrict__ Ul,
    const unsigned short* __restrict__ Vh, const unsigned short* __restrict__ Vl,
    unsigned short* __restrict__ Oh, unsigned short* __restrict__ Ol) {
    __shared__ float red[1024];
    const int tile = blockIdx.x;
    const int i0 = (tile >> 5) * 16, j0 = (tile & 31) * 16;
    const int t = threadIdx.x, w = t >> 6, lane = t & 63;
    const int lm = lane & 15, lq = lane >> 4;
    const size_t ko = (size_t)w * 128;
    f32x4 a1 = {0.f, 0.f, 0.f, 0.f}, a2 = {0.f, 0.f, 0.f, 0.f};
    mm_ks(Uh + (size_t)i0 * M + ko, Ul + (size_t)i0 * M + ko, M,
          Vh + (size_t)j0 * M + ko, Vl + (size_t)j0 * M + ko, M,
          128, lm, lq, a1, a2);
    const float v = splitk_reduce(red, a1 + a2, w, lm, lq, t);
    const size_t idx = (size_t)(i0 + (t >> 4)) * M + j0 + (t & 15);
    const unsigned short h = f2bf(v);
    Oh[idx] = h; Ol[idx] = f2bf(v - bf2f(h));
}

// ---- dual small mm: job0 (tiles 0..1023): O0 = U0·V0; job1: O1 = U1·V1.
__global__ __launch_bounds__(256) void mm_dual(
    const unsigned short* __restrict__ U0h, const unsigned short* __restrict__ U0l,
    const unsigned short* __restrict__ V0h, const unsigned short* __restrict__ V0l,
    unsigned short* __restrict__ O0h, unsigned short* __restrict__ O0l,
    const unsigned short* __restrict__ U1h, const unsigned short* __restrict__ U1l,
    const unsigned short* __restrict__ V1h, const unsigned short* __restrict__ V1l,
    unsigned short* __restrict__ O1h, unsigned short* __restrict__ O1l) {
    __shared__ float red[1024];
    const int unit = blockIdx.x;
    const int job = unit >> 10, tile = unit & 1023;
    const int i0 = (tile >> 5) * 16, j0 = (tile & 31) * 16;
    const int t = threadIdx.x, w = t >> 6, lane = t & 63;
    const int lm = lane & 15, lq = lane >> 4;
    const size_t ko = (size_t)w * 128;
    const unsigned short* Uh = job ? U1h : U0h;
    const unsigned short* Ul = job ? U1l : U0l;
    const unsigned short* Vh = job ? V1h : V0h;
    const unsigned short* Vl = job ? V1l : V0l;
    unsigned short* Oh = job ? O1h : O0h;
    unsigned short* Ol = job ? O1l : O0l;
    f32x4 a1 = {0.f, 0.f, 0.f, 0.f}, a2 = {0.f, 0.f, 0.f, 0.f};
    mm_ks(Uh + (size_t)i0 * M + ko, Ul + (size_t)i0 * M + ko, M,
          Vh + (size_t)j0 * M + ko, Vl + (size_t)j0 * M + ko, M,
          128, lm, lq, a1, a2);
    const float v = splitk_reduce(red, a1 + a2, w, lm, lq, t);
    const size_t idx = (size_t)(i0 + (t >> 4)) * M + j0 + (t & 15);
    const unsigned short h = f2bf(v);
    Oh[idx] = h; Ol[idx] = f2bf(v - bf2f(h));
}

// ---- poly step: W = U·V; P = cA*Ge + cB*Se + cC*W (Ge,Se elementwise);
//      optionally store P hi/lo; always store C = a*I - b*P hi/lo.
__global__ __launch_bounds__(256) void mm_poly(
    const unsigned short* __restrict__ Uh, const unsigned short* __restrict__ Ul,
    const unsigned short* __restrict__ Vh, const unsigned short* __restrict__ Vl,
    const unsigned short* __restrict__ Geh, const unsigned short* __restrict__ Gel,
    const unsigned short* __restrict__ Seh, const unsigned short* __restrict__ Sel,
    unsigned short* __restrict__ Ph, unsigned short* __restrict__ Pl,
    unsigned short* __restrict__ Ch, unsigned short* __restrict__ Cl,
    const float cA, const float cB, const float cC,
    const float a, const float b, const int writeP) {
    __shared__ float red[1024];
    const int tile = blockIdx.x;
    const int i0 = (tile >> 5) * 16, j0 = (tile & 31) * 16;
    const int t = threadIdx.x, w = t >> 6, lane = t & 63;
    const int lm = lane & 15, lq = lane >> 4;
    const size_t ko = (size_t)w * 128;
    f32x4 a1 = {0.f, 0.f, 0.f, 0.f}, a2 = {0.f, 0.f, 0.f, 0.f};
    mm_ks(Uh + (size_t)i0 * M + ko, Ul + (size_t)i0 * M + ko, M,
          Vh + (size_t)j0 * M + ko, Vl + (size_t)j0 * M + ko, M,
          128, lm, lq, a1, a2);
    const float wv = splitk_reduce(red, a1 + a2, w, lm, lq, t);
    const int row = i0 + (t >> 4), col = j0 + (t & 15);
    const size_t idx = (size_t)row * M + col;
    const float p = cA * (bf2f(Geh[idx]) + bf2f(Gel[idx]))
                  + cB * (bf2f(Seh[idx]) + bf2f(Sel[idx]))
                  + cC * wv;
    if (writeP) {
        const unsigned short h = f2bf(p);
        Ph[idx] = h; Pl[idx] = f2bf(p - bf2f(h));
    }
    const float c = (row == col ? a : 0.0f) - b * p;
    const unsigned short h2 = f2bf(c);
    Ch[idx] = h2; Cl[idx] = f2bf(c - bf2f(h2));
}

// ---- final: out = X·B (B symmetric). 4096 tiles, wave per tile, grid 1024.
__global__ __launch_bounds__(256) void final_mm(
    const unsigned short* __restrict__ Xhi, const unsigned short* __restrict__ Xlo,
    const unsigned short* __restrict__ Bh, const unsigned short* __restrict__ Bl,
    float* __restrict__ out) {
    const int t = threadIdx.x;
    const int tile = blockIdx.x * 4 + (t >> 6);   // 0..4095 (128 x 32)
    const int lane = t & 63;
    const int lm = lane & 15, lq = lane >> 4;
    const int i0 = (tile >> 5) * 16, j0 = (tile & 31) * 16;
    f32x4 a1 = {0.f, 0.f, 0.f, 0.f}, a2 = {0.f, 0.f, 0.f, 0.f};
    mm_ks(Xhi + (size_t)i0 * M, Xlo + (size_t)i0 * M, M,
          Bh + (size_t)j0 * M, Bl + (size_t)j0 * M, M,
          512, lm, lq, a1, a2);
    const f32x4 acc = a1 + a2;
    float* o = out + (size_t)(i0 + lq * 4) * M + j0 + lm;
    #pragma unroll
    for (int q = 0; q < 4; ++q) o[(size_t)q * M] = acc[q];
}

extern "C" void kernel_launch(void* const* d_in, const int* in_sizes, int n_in,
                              void* d_out, int out_size, void* d_ws, size_t ws_size,
                              hipStream_t stream) {
    const float* Xin = (const float*)d_in[0];
    float* out = (float*)d_out;
    unsigned short* w = (unsigned short*)d_ws;

    unsigned short* Xhi  = w;                   // D*M = 1048576 each
    unsigned short* Xlo  = w + 1048576u;
    unsigned short* XThi = w + 2097152u;
    unsigned short* XTlo = w + 3145728u;
    unsigned short* q = w + 4194304u;           // M*M = 262144 each below
    unsigned short* G0h = q;            unsigned short* G0l = q + 262144u;
    unsigned short* Sh  = q + 524288u;  unsigned short* Sl  = q + 786432u;
    unsigned short* G1h = q + 1048576u; unsigned short* G1l = q + 1310720u;
    unsigned short* S1h = q + 1572864u; unsigned short* S1l = q + 1835008u;
    unsigned short* C1h = q + 2097152u; unsigned short* C1l = q + 2359296u;
    unsigned short* C2h = q + 2621440u; unsigned short* C2l = q + 2883584u;
    unsigned short* C3h = q + 3145728u; unsigned short* C3l = q + 3407872u;
    unsigned short* B2h = q + 3670016u; unsigned short* B2l = q + 3932160u;
    unsigned short* B3h = q + 4194304u; unsigned short* B3l = q + 4456448u;

    // d1: split + transpose
    trans_split<<<dim3(32, 8), 256, 0, stream>>>(Xin, Xhi, Xlo, XThi, XTlo);
    // d2: G0 = X^T X ; C1 = CA1 I - CB1 G0  (C1 == B1)
    gram_c<<<1024, 256, 0, stream>>>(XThi, XTlo, G0h, G0l, C1h, C1l);
    // d3: S = G0^2
    mm_small<<<1024, 256, 0, stream>>>(G0h, G0l, G0h, G0l, Sh, Sl);
    // d4: G1 = CA1^2 G0 - 2 CA1 CB1 S + CB1^2 (G0·S) ; C2 = CA2 I - CB2 G1
    mm_poly<<<1024, 256, 0, stream>>>(G0h, G0l, Sh, Sl, G0h, G0l, Sh, Sl,
                                      G1h, G1l, C2h, C2l,
                                      CA1 * CA1, -2.0f * CA1 * CB1, CB1 * CB1,
                                      CA2, CB2, 1);
    // d5: S1 = G1^2  ||  B2 = C1·C2
    mm_dual<<<2048, 256, 0, stream>>>(G1h, G1l, G1h, G1l, S1h, S1l,
                                      C1h, C1l, C2h, C2l, B2h, B2l);
    // d6: G2 = CA2^2 G1 - 2 CA2 CB2 S1 + CB2^2 (G1·S1) ; emit C3 only
    mm_poly<<<1024, 256, 0, stream>>>(G1h, G1l, S1h, S1l, G1h, G1l, S1h, S1l,
                                      nullptr, nullptr, C3h, C3l,
                                      CA2 * CA2, -2.0f * CA2 * CB2, CB2 * CB2,
                                      CA3, CB3, 0);
    // d7: B3 = B2·C3
    mm_small<<<1024, 256, 0, stream>>>(B2h, B2l, C3h, C3l, B3h, B3l);
    // d8: out = X·B3
    final_mm<<<1024, 256, 0, stream>>>(Xhi, Xlo, B3h, B3l, out);
}